// Round 1
// baseline (3349.975 us; speedup 1.0000x reference)
//
#include <hip/hip_runtime.h>

// ConvLSTM2D x2, B=4 T=16 H=W=64 Cin=F=32, k=3, SAME zero-pad.
// Interleaved pipeline: for t: L1 step (x_t,h1_{t-1} -> h1_t), L2 step (h1_t,h2_{t-1} -> out[t]).
// ws: h1 double buffer + c1 + c2 = 8 MB.

#define Hdim 64
#define Wdim 64
#define CIN 32
#define FDIM 32
#define BATCH 4
#define TSTEPS 16

__device__ __forceinline__ float fsigmoid(float z) {
    return 1.0f / (1.0f + __expf(-z));
}
__device__ __forceinline__ float ftanh(float z) {
    z = fminf(15.0f, fmaxf(-15.0f, z));
    float e = __expf(2.0f * z);
    return (e - 1.0f) / (e + 1.0f);
}

// HASH = has nonzero previous hidden state (t>0). At t=0, h=c=0: skip h-conv and c-read.
template <bool HASH>
__global__ __launch_bounds__(256) void clstm_step(
    const float* __restrict__ xin, size_t xbs,    // input (B,.,H,W,32) slice base + batch stride
    const float* __restrict__ hprev, size_t hpbs, // prev hidden, same layout semantics
    const float* __restrict__ wk,                 // (3,3,32,128) input kernel
    const float* __restrict__ wr,                 // (3,3,32,128) recurrent kernel
    const float* __restrict__ bias,               // (128)
    float* __restrict__ cbuf,                     // (B,H,W,32) cell state (in/out)
    float* __restrict__ hout, size_t hobs)        // new hidden out + batch stride
{
    const int tid = threadIdx.x;
    const int f   = tid & 31;        // output channel within gate
    const int grp = tid >> 5;        // 0..7 pixel groups
    const int pix0 = blockIdx.x * 32 + grp * 4;   // 4 consecutive W-pixels
    const int b   = pix0 >> 12;      // / (64*64)
    const int rem = pix0 & 4095;
    const int y   = rem >> 6;
    const int x0  = rem & 63;        // multiple of 4 -> 4 pixels stay in-row

    // acc[pixel][gate]: i,f,c~,o
    float acc[4][4];
    const float b0 = bias[f], b1 = bias[32 + f], b2 = bias[64 + f], b3 = bias[96 + f];
    #pragma unroll
    for (int p = 0; p < 4; ++p) { acc[p][0] = b0; acc[p][1] = b1; acc[p][2] = b2; acc[p][3] = b3; }

    const float* xb = xin + (size_t)b * xbs;
    const float* hb = HASH ? (hprev + (size_t)b * hpbs) : nullptr;

    #pragma unroll
    for (int dy = 0; dy < 3; ++dy) {
        const int yy = y + dy - 1;
        if (yy < 0 || yy >= Hdim) continue;   // zero pad row
        const float* xrow = xb + (size_t)yy * (Wdim * CIN);
        const float* hrow = HASH ? (hb + (size_t)yy * (Wdim * FDIM)) : nullptr;
        #pragma unroll
        for (int dx = 0; dx < 3; ++dx) {
            const float* wkp = wk + (size_t)((dy * 3 + dx) * CIN) * 128 + f;
            const float* wrp = wr + (size_t)((dy * 3 + dx) * CIN) * 128 + f;
            for (int ci = 0; ci < CIN; ++ci) {
                const float k0 = wkp[ci * 128];
                const float k1 = wkp[ci * 128 + 32];
                const float k2 = wkp[ci * 128 + 64];
                const float k3 = wkp[ci * 128 + 96];
                float r0 = 0.f, r1 = 0.f, r2 = 0.f, r3 = 0.f;
                if (HASH) {
                    r0 = wrp[ci * 128];
                    r1 = wrp[ci * 128 + 32];
                    r2 = wrp[ci * 128 + 64];
                    r3 = wrp[ci * 128 + 96];
                }
                #pragma unroll
                for (int p = 0; p < 4; ++p) {
                    const int col = x0 + p + dx - 1;
                    if (col < 0 || col >= Wdim) continue;  // zero pad col
                    const float xv = xrow[col * CIN + ci];
                    acc[p][0] = fmaf(xv, k0, acc[p][0]);
                    acc[p][1] = fmaf(xv, k1, acc[p][1]);
                    acc[p][2] = fmaf(xv, k2, acc[p][2]);
                    acc[p][3] = fmaf(xv, k3, acc[p][3]);
                    if (HASH) {
                        const float hv = hrow[col * FDIM + ci];
                        acc[p][0] = fmaf(hv, r0, acc[p][0]);
                        acc[p][1] = fmaf(hv, r1, acc[p][1]);
                        acc[p][2] = fmaf(hv, r2, acc[p][2]);
                        acc[p][3] = fmaf(hv, r3, acc[p][3]);
                    }
                }
            }
        }
    }

    // Gates: Keras order i,f,c,o
    #pragma unroll
    for (int p = 0; p < 4; ++p) {
        const int xw = x0 + p;
        const size_t cidx = (((size_t)b * Hdim + y) * Wdim + xw) * FDIM + f;
        const float ig = fsigmoid(acc[p][0]);
        const float fg = fsigmoid(acc[p][1]);
        const float gg = ftanh(acc[p][2]);
        const float og = fsigmoid(acc[p][3]);
        const float cold = HASH ? cbuf[cidx] : 0.0f;
        const float cnew = fg * cold + ig * gg;
        cbuf[cidx] = cnew;
        hout[(size_t)b * hobs + ((size_t)y * Wdim + xw) * FDIM + f] = og * ftanh(cnew);
    }
}

extern "C" void kernel_launch(void* const* d_in, const int* in_sizes, int n_in,
                              void* d_out, int out_size, void* d_ws, size_t ws_size,
                              hipStream_t stream)
{
    const float* x   = (const float*)d_in[0];
    const float* k1  = (const float*)d_in[1];
    const float* rk1 = (const float*)d_in[2];
    const float* b1  = (const float*)d_in[3];
    const float* k2  = (const float*)d_in[4];
    const float* rk2 = (const float*)d_in[5];
    const float* b2  = (const float*)d_in[6];
    float* out = (float*)d_out;

    const size_t planeF = (size_t)Hdim * Wdim * FDIM;   // 131072 elems per (b) plane
    const size_t planeC = (size_t)Hdim * Wdim * CIN;

    float* h1a = (float*)d_ws;                 // (B,H,W,F)
    float* h1b = h1a + (size_t)BATCH * planeF; // (B,H,W,F)
    float* c1  = h1b + (size_t)BATCH * planeF; // (B,H,W,F)
    float* c2  = c1  + (size_t)BATCH * planeF; // (B,H,W,F)

    dim3 grid(512), block(256);

    for (int t = 0; t < TSTEPS; ++t) {
        float* h1cur  = (t & 1) ? h1b : h1a;
        float* h1prev = (t & 1) ? h1a : h1b;
        if (t == 0) {
            // Layer 1, t=0: h=c=0
            clstm_step<false><<<grid, block, 0, stream>>>(
                x, (size_t)TSTEPS * planeC,
                nullptr, 0,
                k1, rk1, b1, c1, h1cur, planeF);
            // Layer 2, t=0
            clstm_step<false><<<grid, block, 0, stream>>>(
                h1cur, planeF,
                nullptr, 0,
                k2, rk2, b2, c2,
                out, (size_t)TSTEPS * planeF);
        } else {
            clstm_step<true><<<grid, block, 0, stream>>>(
                x + (size_t)t * planeC, (size_t)TSTEPS * planeC,
                h1prev, planeF,
                k1, rk1, b1, c1, h1cur, planeF);
            clstm_step<true><<<grid, block, 0, stream>>>(
                h1cur, planeF,
                out + (size_t)(t - 1) * planeF, (size_t)TSTEPS * planeF,
                k2, rk2, b2, c2,
                out + (size_t)t * planeF, (size_t)TSTEPS * planeF);
        }
    }
}

// Round 2
// 318.121 us; speedup vs baseline: 10.5305x; 10.5305x over previous
//
#include <hip/hip_runtime.h>

// ConvLSTM2D x2 via implicit-GEMM MFMA (bf16 inputs, fp32 accum).
// B=4 T=16 H=W=64 Cin=F=32, k=3 SAME. Per step: M=16384, N=128, K=576.
// Weights pre-packed to fragment-native layout with gate-permuted columns
// so all 4 gates of one (pixel,f) land in one lane's accumulators.

typedef __bf16 bf16x8 __attribute__((ext_vector_type(8)));
typedef float f32x4 __attribute__((ext_vector_type(4)));

#define Hdim 64
#define Wdim 64
#define CIN 32
#define FDIM 32
#define BATCH 4
#define TSTEPS 16

#define WPK_ELEMS 73728   // 18 kchunks * 8 ntiles * 64 lanes * 8

__device__ __forceinline__ float fsigmoid(float z) {
    return 1.0f / (1.0f + __expf(-z));
}
__device__ __forceinline__ float ftanh(float z) {
    z = fminf(15.0f, fmaxf(-15.0f, z));
    float e = __expf(2.0f * z);
    return (e - 1.0f) / (e + 1.0f);
}

// Pack wk/wr (3,3,32,128) fp32 -> wpk[layer][cix][nt][lane][j2] bf16.
// cix = tap*2 + src (src 0 = input kernel, 1 = recurrent kernel).
// GEMM column n' = nt*16 + (lane&15); maps to original n = gate*32 + f with
// gate = nt&3, f = (nt>>2)*16 + (lane&15).  K-in-chunk = (lane>>4)*8 + j2.
__global__ __launch_bounds__(256) void pack_weights(
    const float* __restrict__ wk1, const float* __restrict__ wr1,
    const float* __restrict__ wk2, const float* __restrict__ wr2,
    __bf16* __restrict__ wpk)
{
    int i = blockIdx.x * 256 + threadIdx.x;
    if (i >= 2 * WPK_ELEMS) return;
    int layer = i / WPK_ELEMS;
    int r = i - layer * WPK_ELEMS;
    int j2 = r & 7;
    int L  = (r >> 3) & 63;
    int nt = (r >> 9) & 7;
    int cix = r >> 12;            // 0..17
    int tap = cix >> 1, src = cix & 1;
    int s = ((L >> 4) << 3) + j2;            // channel 0..31
    int gate = nt & 3;
    int f = ((nt >> 2) << 4) + (L & 15);     // 0..31
    int n = (gate << 5) + f;                 // original col in (...,128)
    const float* w = layer ? (src ? wr2 : wk2) : (src ? wr1 : wk1);
    wpk[i] = (__bf16)w[(tap * 32 + s) * 128 + n];
}

// One ConvLSTM step for one layer over all B*H*W pixels.
// Block = half row (32 pixels), 512 blocks, 256 threads (4 waves, 2M x 2N).
template <bool HASH>
__global__ __launch_bounds__(256, 2) void clstm_mfma(
    const float* __restrict__ xin, size_t xbs,     // conv input, fp32, + batch stride
    const float* __restrict__ hprev, size_t hpbs,  // prev hidden, fp32
    const __bf16* __restrict__ wpk,                // packed weights (one layer)
    const float* __restrict__ bias,                // (128,) gate order i,f,c,o
    float* __restrict__ cbuf,                      // (B,H,W,32) cell state
    float* __restrict__ hout, size_t hobs)         // new hidden + batch stride
{
    // LDS halo tiles: 3 rows x 34 cols x 32 ch, stride 56 bf16 (112 B) to
    // break bank-column alignment (period-8 -> free 2-way conflicts).
    __shared__ __bf16 xlds[3 * 34 * 56];
    __shared__ __bf16 hlds[3 * 34 * 56];

    const int tid = threadIdx.x;
    const int blk = blockIdx.x;
    const int b  = blk >> 7;
    const int y  = (blk >> 1) & 63;
    const int xh = (blk & 1) * 32;

    const float* xb = xin + (size_t)b * xbs;
    const float* hb = HASH ? (hprev + (size_t)b * hpbs) : nullptr;

    // ---- Stage x (and h) halo rows, fp32 -> bf16 ----
    const int NCH = HASH ? 816 : 408;   // 2|1 src * 3 dy * 34 cc * 4 g
    for (int i = tid; i < NCH; i += 256) {
        int src = i / 408;
        int rem = i - src * 408;
        int dy = rem / 136;
        int rem2 = rem - dy * 136;
        int cc = rem2 >> 2;          // 0..33
        int g  = rem2 & 3;           // 8-channel group
        int yy = y + dy - 1;
        int xc = xh - 1 + cc;
        bf16x8 v = {};
        if (yy >= 0 && yy < Hdim && xc >= 0 && xc < Wdim) {
            const float* p = (src ? hb : xb) + (((size_t)yy * Wdim + xc) * 32 + g * 8);
            const float4 f0 = *(const float4*)p;
            const float4 f1 = *(const float4*)(p + 4);
            v[0] = (__bf16)f0.x; v[1] = (__bf16)f0.y;
            v[2] = (__bf16)f0.z; v[3] = (__bf16)f0.w;
            v[4] = (__bf16)f1.x; v[5] = (__bf16)f1.y;
            v[6] = (__bf16)f1.z; v[7] = (__bf16)f1.w;
        }
        __bf16* dst = (src ? hlds : xlds) + (dy * 34 + cc) * 56 + g * 8;
        *(bf16x8*)dst = v;
    }
    __syncthreads();

    // ---- K-loop: 9 taps x {x, h} K=32 chunks ----
    const int w  = tid >> 6;        // wave 0..3
    const int L  = tid & 63;
    const int wm = w >> 1;          // M half (16 pixels)
    const int wn = w & 1;           // N half (f in [16wn,16wn+16))
    const int c  = L & 15;
    const int q  = L >> 4;
    const int ccb = wm * 16 + c;    // lane's A column base in LDS cols
    const int q8  = q * 8;
    const int wn4 = wn * 4;
    const bf16x8* wpkv = (const bf16x8*)wpk;

    f32x4 accI = {0.f, 0.f, 0.f, 0.f};
    f32x4 accF = {0.f, 0.f, 0.f, 0.f};
    f32x4 accG = {0.f, 0.f, 0.f, 0.f};
    f32x4 accO = {0.f, 0.f, 0.f, 0.f};

    #pragma unroll
    for (int tap = 0; tap < 9; ++tap) {
        const int dy = tap / 3;
        const int dx = tap - dy * 3;
        const int aoff = (dy * 34 + ccb + dx) * 56 + q8;
        const bf16x8 ax = *(const bf16x8*)(xlds + aoff);
        const bf16x8* wbx = wpkv + ((2 * tap) * 8 + wn4) * 64 + L;
        accI = __builtin_amdgcn_mfma_f32_16x16x32_bf16(ax, wbx[0],       accI, 0, 0, 0);
        accF = __builtin_amdgcn_mfma_f32_16x16x32_bf16(ax, wbx[64],      accF, 0, 0, 0);
        accG = __builtin_amdgcn_mfma_f32_16x16x32_bf16(ax, wbx[128],     accG, 0, 0, 0);
        accO = __builtin_amdgcn_mfma_f32_16x16x32_bf16(ax, wbx[192],     accO, 0, 0, 0);
        if (HASH) {
            const bf16x8 ah = *(const bf16x8*)(hlds + aoff);
            const bf16x8* wbh = wpkv + ((2 * tap + 1) * 8 + wn4) * 64 + L;
            accI = __builtin_amdgcn_mfma_f32_16x16x32_bf16(ah, wbh[0],   accI, 0, 0, 0);
            accF = __builtin_amdgcn_mfma_f32_16x16x32_bf16(ah, wbh[64],  accF, 0, 0, 0);
            accG = __builtin_amdgcn_mfma_f32_16x16x32_bf16(ah, wbh[128], accG, 0, 0, 0);
            accO = __builtin_amdgcn_mfma_f32_16x16x32_bf16(ah, wbh[192], accO, 0, 0, 0);
        }
    }

    // ---- Gating epilogue (all 4 gates lane-local) ----
    const int f = wn * 16 + c;
    const float bI = bias[f], bF = bias[32 + f], bG = bias[64 + f], bO = bias[96 + f];
    #pragma unroll
    for (int r = 0; r < 4; ++r) {
        const int m  = wm * 16 + q * 4 + r;   // pixel within 32-tile
        const int xw = xh + m;
        const size_t cidx = (((size_t)b * Hdim + y) * Wdim + xw) * FDIM + f;
        const float ig = fsigmoid(accI[r] + bI);
        const float fg = fsigmoid(accF[r] + bF);
        const float gg = ftanh(accG[r] + bG);
        const float og = fsigmoid(accO[r] + bO);
        const float cold = HASH ? cbuf[cidx] : 0.0f;
        const float cnew = fg * cold + ig * gg;
        cbuf[cidx] = cnew;
        hout[(size_t)b * hobs + (((size_t)y * Wdim + xw) * FDIM + f)] = og * ftanh(cnew);
    }
}

extern "C" void kernel_launch(void* const* d_in, const int* in_sizes, int n_in,
                              void* d_out, int out_size, void* d_ws, size_t ws_size,
                              hipStream_t stream)
{
    const float* x   = (const float*)d_in[0];
    const float* k1  = (const float*)d_in[1];
    const float* rk1 = (const float*)d_in[2];
    const float* b1  = (const float*)d_in[3];
    const float* k2  = (const float*)d_in[4];
    const float* rk2 = (const float*)d_in[5];
    const float* b2  = (const float*)d_in[6];
    float* out = (float*)d_out;

    const size_t planeF = (size_t)Hdim * Wdim * FDIM;   // 131072
    const size_t planeC = (size_t)Hdim * Wdim * CIN;

    __bf16* wpk1 = (__bf16*)d_ws;
    __bf16* wpk2 = wpk1 + WPK_ELEMS;
    float* fbase = (float*)(wpk1 + 2 * WPK_ELEMS);      // 294912 B offset, aligned
    float* h1a = fbase;
    float* h1b = h1a + (size_t)BATCH * planeF;
    float* c1  = h1b + (size_t)BATCH * planeF;
    float* c2  = c1  + (size_t)BATCH * planeF;

    pack_weights<<<(2 * WPK_ELEMS + 255) / 256, 256, 0, stream>>>(k1, rk1, k2, rk2, wpk1);

    dim3 grid(512), block(256);
    for (int t = 0; t < TSTEPS; ++t) {
        float* h1cur  = (t & 1) ? h1b : h1a;
        float* h1prev = (t & 1) ? h1a : h1b;
        if (t == 0) {
            clstm_mfma<false><<<grid, block, 0, stream>>>(
                x, (size_t)TSTEPS * planeC,
                nullptr, 0,
                wpk1, b1, c1, h1cur, planeF);
            clstm_mfma<false><<<grid, block, 0, stream>>>(
                h1cur, planeF,
                nullptr, 0,
                wpk2, b2, c2,
                out, (size_t)TSTEPS * planeF);
        } else {
            clstm_mfma<true><<<grid, block, 0, stream>>>(
                x + (size_t)t * planeC, (size_t)TSTEPS * planeC,
                h1prev, planeF,
                wpk1, b1, c1, h1cur, planeF);
            clstm_mfma<true><<<grid, block, 0, stream>>>(
                h1cur, planeF,
                out + (size_t)(t - 1) * planeF, (size_t)TSTEPS * planeF,
                wpk2, b2, c2,
                out + (size_t)t * planeF, (size_t)TSTEPS * planeF);
        }
    }
}